// Round 4
// baseline (629.193 us; speedup 1.0000x reference)
//
#include <hip/hip_runtime.h>

// ModulatedConv2d: B=16, C=512->512, 3x3 SAME, per-sample demodulated weights.
// R3: safe pipelined conv. 128o x 256px block, 4 waves (m4 x n8).
//  - sA double-buffered via global_load_lds, counted vmcnt(4) (T3/T4):
//    issue A(ph+1) each tap; invariant: entering a tap, 4 loads outstanding.
//  - sX single buffer, restaged per 64-chan chunk via global_load_lds issued
//    at chunk start (right after prev chunk's last barrier); issue order
//    A(ph) < X < A(ph+1) makes vmcnt(4) drain exactly {A(ph), X}.
//  - No asm register loads (R2's NaN suspect: async "=v" regs spilling).
//  - T2 XOR chunk-swizzle on both tiles (R1: conflicts 1.13e8 -> 0), T5
//    setprio, sched_barrier fences per rule #18.

typedef __bf16 bf16x8 __attribute__((ext_vector_type(8)));
typedef float f32x4 __attribute__((ext_vector_type(4)));

__device__ __forceinline__ void async16(const void* g, void* s) {
  __builtin_amdgcn_global_load_lds((const __attribute__((address_space(1))) void*)g,
                                   (__attribute__((address_space(3))) void*)s, 16, 0, 0);
}

// style[b][i] = dot(w_embs[b,:], style_W[i,:]) + style_b[i] + 1
__global__ __launch_bounds__(256) void k_style(const float* __restrict__ we,
                                               const float* __restrict__ sW,
                                               const float* __restrict__ sb,
                                               float* __restrict__ style) {
  int lane = threadIdx.x & 63, wid = threadIdx.x >> 6;
  int b = blockIdx.x >> 7;
  int i = ((blockIdx.x & 127) << 2) + wid;
  const float* wer = we + b * 512;
  const float* swr = sW + i * 512;
  float acc = 0.f;
  for (int d = lane; d < 512; d += 64) acc += wer[d] * swr[d];
#pragma unroll
  for (int off = 32; off; off >>= 1) acc += __shfl_xor(acc, off);
  if (lane == 0) style[b * 512 + i] = acc + sb[i] + 1.0f;
}

// wsq[o][i] = sum_k cw[o][i][k]^2
__global__ __launch_bounds__(256) void k_wsq(const float* __restrict__ cw,
                                             float* __restrict__ wsq) {
  int t = blockIdx.x * 256 + threadIdx.x;  // o*512+i
  const float* p = cw + (long)t * 9;
  float s = 0.f;
#pragma unroll
  for (int k = 0; k < 9; ++k) s += p[k] * p[k];
  wsq[t] = s;
}

// rnorm[b][o] = rsqrt(sum_i style[b,i]^2 * wsq[o,i])
__global__ __launch_bounds__(256) void k_rnorm(const float* __restrict__ style,
                                               const float* __restrict__ wsq,
                                               float* __restrict__ rnorm) {
  int lane = threadIdx.x & 63, wid = threadIdx.x >> 6;
  int idx = blockIdx.x * 4 + wid;  // b*512 + o
  int b = idx >> 9, o = idx & 511;
  float acc = 0.f;
  for (int i = lane; i < 512; i += 64) {
    float s = style[(b << 9) + i];
    acc += s * s * wsq[(o << 9) + i];
  }
#pragma unroll
  for (int off = 32; off; off >>= 1) acc += __shfl_xor(acc, off);
  if (lane == 0) rnorm[idx] = rsqrtf(acc);
}

// wt[b][t][o][i] = bf16( cw[o][i][t] * style[b][i] * rnorm[b][o] )
__global__ __launch_bounds__(256) void k_wt(const float* __restrict__ cw,
                                            const float* __restrict__ style,
                                            const float* __restrict__ rnorm,
                                            __bf16* __restrict__ wt) {
  int t = blockIdx.x * 256 + threadIdx.x;  // b*262144 + o*512 + i
  int b = t >> 18;
  int oi = t & 262143;
  int o = oi >> 9, i = oi & 511;
  float sc = style[(b << 9) + i] * rnorm[(b << 9) + o];
  const float* p = cw + (long)oi * 9;
#pragma unroll
  for (int k = 0; k < 9; ++k)
    wt[((long)(b * 9 + k) << 18) + ((long)o << 9) + i] = (__bf16)(p[k] * sc);
}

// xpad[b][r][c][i] (r,c in [0,66)) = bf16(imgs[b][i][r-1][c-1]), zero border.
__global__ __launch_bounds__(256) void k_xpad(const float* __restrict__ imgs,
                                              __bf16* __restrict__ xpad) {
  int t = blockIdx.x * 256 + threadIdx.x;  // b*4356 + r*66 + c
  if (t >= 16 * 4356) return;
  int b = t / 4356;
  int rc = t - b * 4356;
  int r = rc / 66, c = rc - (rc / 66) * 66;
  __bf16* dst = xpad + (long)t * 512;
  if (r == 0 || r == 65 || c == 0 || c == 65) {
    const f32x4 z = {0.f, 0.f, 0.f, 0.f};
#pragma unroll 4
    for (int j = 0; j < 64; ++j) *(f32x4*)(dst + j * 8) = z;
  } else {
    const float* src = imgs + ((long)b << 21) + ((r - 1) << 6) + (c - 1);
    for (int j = 0; j < 64; ++j) {
      bf16x8 v;
#pragma unroll
      for (int q = 0; q < 8; ++q) v[q] = (__bf16)src[(long)(j * 8 + q) << 12];
      *(bf16x8*)(dst + j * 8) = v;
    }
  }
}

// Conv: block = 128 o x 256 px (8h x 32w), 4 waves of 64o x 128px (m4 n8).
// sX: 340 px (10r x 34c) x 64 ch, padded to 2816 16B slots (45056 B).
// sA: 2 x (128 x 64) bf16 (2 x 16384 B). LDS total 77824 B -> 2 blocks/CU.
__global__ __launch_bounds__(256, 2) void k_conv(const __bf16* __restrict__ xpad,
                                                 const __bf16* __restrict__ wt,
                                                 const float* __restrict__ bias,
                                                 float* __restrict__ out) {
  __shared__ __attribute__((aligned(16))) __bf16 sAe[2 * 8192];
  __shared__ __attribute__((aligned(16))) __bf16 sX[22528];

  const int tid = threadIdx.x;
  const int lane = tid & 63;
  const int wid = tid >> 6;
  const int wo = wid >> 1, wp = wid & 1;
  const int l15 = lane & 15, lq = lane >> 4, l7 = lane & 7;

  const int bid = blockIdx.x;
  const int b = bid >> 6;          // 64 blocks / batch
  const int r6 = bid & 63;
  const int o0 = (r6 >> 4) << 7;   // 4 o-tiles of 128
  const int st = r6 & 15;          // 16 spatial tiles
  const int h0 = (st >> 1) << 3;   // 8 h-tiles * 8 rows
  const int w0 = (st & 1) << 5;    // 2 w-tiles * 32 cols
  const int b66 = b * 66;

  // X staging source pointers (chunk 0), slot s = it*256+tid, clamped.
  const __bf16* xg[11];
#pragma unroll
  for (int it = 0; it < 11; ++it) {
    int s = it * 256 + tid;
    if (s > 2719) s = 2719;            // tail slots -> dummy src, dest = LDS pad
    int p = s >> 3;
    int j = (s & 7) ^ (p & 7);         // T2 chunk swizzle
    int lr = p / 34, lc = p - (p / 34) * 34;
    xg[it] = xpad + ((long)((b66 + h0 + lr) * 66) + (w0 + lc)) * 512 + j * 8;
  }
  // A staging source offset (elements), pre-swizzled; stride per it = 16384.
  int aoff0;
  {
    int row = tid >> 3;
    int j = (tid & 7) ^ (row & 7);
    aoff0 = ((o0 + row) << 9) + (j << 3);
  }
  const __bf16* wtb = wt + (long)b * 2359296;

  f32x4 acc[4][8];
  const f32x4 zero4 = {0.f, 0.f, 0.f, 0.f};
#pragma unroll
  for (int m = 0; m < 4; ++m)
#pragma unroll
    for (int n = 0; n < 8; ++n) acc[m][n] = zero4;

  int pbase[4];  // px -> sX row*34+col for this lane; +68 for nh=1
#pragma unroll
  for (int n = 0; n < 4; ++n) {
    int nn = (wp << 7) + (n << 4) + l15;
    pbase[n] = (nn >> 5) * 34 + (nn & 31);
  }
  const int arowb = ((wo << 6) + l15) << 6;

  // ---- prologue: X(chunk 0) + A(ph=0) into buf0, full drain ----
#pragma unroll
  for (int it = 0; it < 11; ++it)
    async16(xg[it], (char*)sX + it * 4096 + (wid << 10));
#pragma unroll
  for (int it = 0; it < 4; ++it)
    async16(wtb + aoff0 + it * 16384, (char*)sAe + it * 4096 + (wid << 10));
  asm volatile("s_waitcnt vmcnt(0)" ::: "memory");
  __builtin_amdgcn_sched_barrier(0);
  __builtin_amdgcn_s_barrier();

  for (int icb = 0; icb < 8; ++icb) {
    const int ic = icb << 6;
#pragma unroll
    for (int t = 0; t < 9; ++t) {
      const int cur = (icb + t) & 1;  // == ph & 1
      // ---- X restage for THIS chunk (issued before A(ph+1): older) ----
      if (t == 0 && icb > 0) {
#pragma unroll
        for (int it = 0; it < 11; ++it)
          async16(xg[it] + ic, (char*)sX + it * 4096 + (wid << 10));
      }
      // ---- issue A(ph+1) into the other buffer ----
      if (!(icb == 7 && t == 8)) {
        const int tn = (t == 8) ? 0 : t + 1;
        const int icn = ic + ((t == 8) ? 64 : 0);
        const __bf16* wa = wtb + tn * 262144 + icn + aoff0;
        char* dst = (char*)sAe + (cur ^ 1) * 16384 + (wid << 10);
#pragma unroll
        for (int it = 0; it < 4; ++it) async16(wa + it * 16384, dst + it * 4096);
      }
      // ---- counted wait: A(ph) [+X at t==0] done; A(ph+1) stays in flight --
      if (icb == 7 && t == 8) {
        asm volatile("s_waitcnt vmcnt(0)" ::: "memory");
      } else {
        asm volatile("s_waitcnt vmcnt(4)" ::: "memory");
      }
      __builtin_amdgcn_sched_barrier(0);
      __builtin_amdgcn_s_barrier();
      __builtin_amdgcn_sched_barrier(0);
      // ---- compute tap t from sAe[cur], sX ----
      const int ky = t / 3, kx = t - (t / 3) * 3;
      const int kshift = ky * 34 + kx;
      const __bf16* sAb = sAe + cur * 8192;
      __builtin_amdgcn_s_setprio(1);
#pragma unroll
      for (int kk = 0; kk < 2; ++kk) {
        const int jb = lq + (kk << 2);
        const int jA = (jb ^ l7) << 3;
        bf16x8 af[4];
#pragma unroll
        for (int m = 0; m < 4; ++m)
          af[m] = *(const bf16x8*)&sAb[arowb + (m << 10) + jA];
#pragma unroll
        for (int nh = 0; nh < 2; ++nh) {
          bf16x8 bfr[4];
#pragma unroll
          for (int n2 = 0; n2 < 4; ++n2) {
            int p = pbase[n2] + nh * 68 + kshift;
            bfr[n2] = *(const bf16x8*)&sX[(p << 6) + ((jb ^ (p & 7)) << 3)];
          }
#pragma unroll
          for (int m = 0; m < 4; ++m)
#pragma unroll
            for (int n2 = 0; n2 < 4; ++n2)
              acc[m][(nh << 2) + n2] = __builtin_amdgcn_mfma_f32_16x16x32_bf16(
                  af[m], bfr[n2], acc[m][(nh << 2) + n2], 0, 0, 0);
        }
      }
      __builtin_amdgcn_s_setprio(0);
      __builtin_amdgcn_sched_barrier(0);
      __builtin_amdgcn_s_barrier();
    }
  }

  // Epilogue: C/D col=lane&15 (pixel), row=(lane>>4)*4+q (out chan).
  float* outb = out + ((long)b << 21);
#pragma unroll
  for (int m = 0; m < 4; ++m) {
    int ob = o0 + (wo << 6) + (m << 4) + (lq << 2);
#pragma unroll
    for (int n = 0; n < 8; ++n) {
      int pid = (wp << 7) + (n << 4) + l15;
      int h = h0 + (pid >> 5), w = w0 + (pid & 31);
#pragma unroll
      for (int q = 0; q < 4; ++q) {
        int o = ob + q;
        outb[((long)o << 12) + (h << 6) + w] = acc[m][n][q] + bias[o];
      }
    }
  }
}

extern "C" void kernel_launch(void* const* d_in, const int* in_sizes, int n_in,
                              void* d_out, int out_size, void* d_ws, size_t ws_size,
                              hipStream_t stream) {
  const float* imgs = (const float*)d_in[0];
  const float* w_embs = (const float*)d_in[1];
  const float* cw = (const float*)d_in[2];
  const float* bias = (const float*)d_in[3];
  const float* style_W = (const float*)d_in[4];
  const float* style_b = (const float*)d_in[5];
  float* out = (float*)d_out;

  char* ws = (char*)d_ws;
  float* style = (float*)(ws);                          // 32 KB
  float* rnorm = (float*)(ws + (32 << 10));             // 32 KB
  float* wsq = (float*)(ws + (64 << 10));               // 1 MB
  __bf16* wt = (__bf16*)(ws + (64 << 10) + (1 << 20));  // 75,497,472 B
  __bf16* xpad = (__bf16*)(ws + (64 << 10) + (1 << 20) + 75497472);  // 71,368,704 B
  size_t need = (size_t)(64 << 10) + (1 << 20) + 75497472ull + 71368704ull;
  if (ws_size < need) return;  // leaves d_out poisoned -> visible failure mode

  k_style<<<2048, 256, 0, stream>>>(w_embs, style_W, style_b, style);
  k_wsq<<<1024, 256, 0, stream>>>(cw, wsq);
  k_rnorm<<<2048, 256, 0, stream>>>(style, wsq, rnorm);
  k_wt<<<16384, 256, 0, stream>>>(cw, style, rnorm, wt);
  k_xpad<<<273, 256, 0, stream>>>(imgs, xpad);
  k_conv<<<1024, 256, 0, stream>>>(xpad, wt, bias, out);
}

// Round 5
// 427.769 us; speedup vs baseline: 1.4709x; 1.4709x over previous
//
#include <hip/hip_runtime.h>

// ModulatedConv2d: B=16, C=512->512, 3x3 SAME, per-sample demodulated weights.
// R4: R1's proven m4n4 128o x 128px kernel (311 us, 84 VGPR + 64 AGPR, no
// spill) + ONE change: sA double-buffer with counted vmcnt(4) + 2 raw
// barriers/tap (T3/T4; schedule proven correct in R3). R3's regression was
// register spill from acc[4][8]=128 AGPR at the 256-reg cap (VGPR_Count=128,
// FETCH/WRITE inflated by ~450MB of scratch) - NOT the schedule.
// LDS: sX 28672 + sA 2x16384 = 61440 B -> 2 blocks/CU (8 waves).

typedef __bf16 bf16x8 __attribute__((ext_vector_type(8)));
typedef float f32x4 __attribute__((ext_vector_type(4)));

__device__ __forceinline__ void async16(const void* g, void* s) {
  __builtin_amdgcn_global_load_lds((const __attribute__((address_space(1))) void*)g,
                                   (__attribute__((address_space(3))) void*)s, 16, 0, 0);
}

// style[b][i] = dot(w_embs[b,:], style_W[i,:]) + style_b[i] + 1
__global__ __launch_bounds__(256) void k_style(const float* __restrict__ we,
                                               const float* __restrict__ sW,
                                               const float* __restrict__ sb,
                                               float* __restrict__ style) {
  int lane = threadIdx.x & 63, wid = threadIdx.x >> 6;
  int b = blockIdx.x >> 7;
  int i = ((blockIdx.x & 127) << 2) + wid;
  const float* wer = we + b * 512;
  const float* swr = sW + i * 512;
  float acc = 0.f;
  for (int d = lane; d < 512; d += 64) acc += wer[d] * swr[d];
#pragma unroll
  for (int off = 32; off; off >>= 1) acc += __shfl_xor(acc, off);
  if (lane == 0) style[b * 512 + i] = acc + sb[i] + 1.0f;
}

// wsq[o][i] = sum_k cw[o][i][k]^2
__global__ __launch_bounds__(256) void k_wsq(const float* __restrict__ cw,
                                             float* __restrict__ wsq) {
  int t = blockIdx.x * 256 + threadIdx.x;  // o*512+i
  const float* p = cw + (long)t * 9;
  float s = 0.f;
#pragma unroll
  for (int k = 0; k < 9; ++k) s += p[k] * p[k];
  wsq[t] = s;
}

// rnorm[b][o] = rsqrt(sum_i style[b,i]^2 * wsq[o,i])
__global__ __launch_bounds__(256) void k_rnorm(const float* __restrict__ style,
                                               const float* __restrict__ wsq,
                                               float* __restrict__ rnorm) {
  int lane = threadIdx.x & 63, wid = threadIdx.x >> 6;
  int idx = blockIdx.x * 4 + wid;  // b*512 + o
  int b = idx >> 9, o = idx & 511;
  float acc = 0.f;
  for (int i = lane; i < 512; i += 64) {
    float s = style[(b << 9) + i];
    acc += s * s * wsq[(o << 9) + i];
  }
#pragma unroll
  for (int off = 32; off; off >>= 1) acc += __shfl_xor(acc, off);
  if (lane == 0) rnorm[idx] = rsqrtf(acc);
}

// wt[b][t][o][i] = bf16( cw[o][i][t] * style[b][i] * rnorm[b][o] )
__global__ __launch_bounds__(256) void k_wt(const float* __restrict__ cw,
                                            const float* __restrict__ style,
                                            const float* __restrict__ rnorm,
                                            __bf16* __restrict__ wt) {
  int t = blockIdx.x * 256 + threadIdx.x;  // b*262144 + o*512 + i
  int b = t >> 18;
  int oi = t & 262143;
  int o = oi >> 9, i = oi & 511;
  float sc = style[(b << 9) + i] * rnorm[(b << 9) + o];
  const float* p = cw + (long)oi * 9;
#pragma unroll
  for (int k = 0; k < 9; ++k)
    wt[((long)(b * 9 + k) << 18) + ((long)o << 9) + i] = (__bf16)(p[k] * sc);
}

// xpad[b][r][c][i] (r,c in [0,66)) = bf16(imgs[b][i][r-1][c-1]), zero border.
__global__ __launch_bounds__(256) void k_xpad(const float* __restrict__ imgs,
                                              __bf16* __restrict__ xpad) {
  int t = blockIdx.x * 256 + threadIdx.x;  // b*4356 + r*66 + c
  if (t >= 16 * 4356) return;
  int b = t / 4356;
  int rc = t - b * 4356;
  int r = rc / 66, c = rc - (rc / 66) * 66;
  __bf16* dst = xpad + (long)t * 512;
  if (r == 0 || r == 65 || c == 0 || c == 65) {
    const f32x4 z = {0.f, 0.f, 0.f, 0.f};
#pragma unroll 4
    for (int j = 0; j < 64; ++j) *(f32x4*)(dst + j * 8) = z;
  } else {
    const float* src = imgs + ((long)b << 21) + ((r - 1) << 6) + (c - 1);
    for (int j = 0; j < 64; ++j) {
      bf16x8 v;
#pragma unroll
      for (int q = 0; q < 8; ++q) v[q] = (__bf16)src[(long)(j * 8 + q) << 12];
      *(bf16x8*)(dst + j * 8) = v;
    }
  }
}

// Conv: block = 128 out-chans x 128 px (4h x 32w), 4 waves (2x2 of 64x64),
// K staged 64 chans/iter, 9 taps inner, mfma 16x16x32 bf16.
// sA double-buffered; per tap: issue A(ph+1) -> buf[cur^1], vmcnt(4) keeps
// it in flight across the barrier; X restaged once per chunk at t==0.
__global__ __launch_bounds__(256, 2) void k_conv(const __bf16* __restrict__ xpad,
                                                 const __bf16* __restrict__ wt,
                                                 const float* __restrict__ bias,
                                                 float* __restrict__ out) {
  __shared__ __attribute__((aligned(16))) __bf16 sX[224 * 64];   // 204 px used
  __shared__ __attribute__((aligned(16))) __bf16 sAe[2 * 8192];  // dbuf 128x64

  const int tid = threadIdx.x;
  const int lane = tid & 63;
  const int wid = tid >> 6;
  const int wr = wid >> 1, wc = wid & 1;
  const int l15 = lane & 15, lq = lane >> 4, l7 = lane & 7;

  const int bid = blockIdx.x;
  const int b = bid >> 7;          // 128 blocks / batch
  const int r7 = bid & 127;
  const int o0 = (r7 >> 5) << 7;   // 4 o-tiles of 128
  const int st = r7 & 31;          // 32 spatial tiles
  const int h0 = (st >> 1) << 2;   // 16 h-tiles * 4 rows
  const int w0 = (st & 1) << 5;    // 2 w-tiles * 32 cols

  // X staging: 1792 16B slots; slot s -> px p=s>>3, holds chunk (s&7)^(p&7).
  const __bf16* xg[7];
#pragma unroll
  for (int it = 0; it < 7; ++it) {
    int s = it * 256 + tid;
    int p = s >> 3;
    int pp = (p < 204) ? p : 0;  // pad slots read dummy, never consumed
    int j = (s & 7) ^ (pp & 7);
    int lr = pp / 34, lc = pp - lr * 34;
    xg[it] = xpad + ((long)((b * 66 + h0 + lr) * 66) + (w0 + lc)) * 512 + j * 8;
  }
  // A staging source offset (elements), pre-swizzled; per-it stride = 16384.
  int aoff0;
  {
    int row = tid >> 3;
    int j = (tid & 7) ^ (row & 7);
    aoff0 = ((o0 + row) << 9) + (j << 3);
  }
  const __bf16* wtb = wt + (long)b * 2359296;

  f32x4 acc[4][4];
  const f32x4 zero4 = {0.f, 0.f, 0.f, 0.f};
#pragma unroll
  for (int m = 0; m < 4; ++m)
#pragma unroll
    for (int n = 0; n < 4; ++n) acc[m][n] = zero4;

  int prn[4], pcn[4];
#pragma unroll
  for (int n = 0; n < 4; ++n) {
    int nn = (wc << 6) + (n << 4) + l15;
    prn[n] = nn >> 5;
    pcn[n] = nn & 31;
  }
  const int arowb = ((wr << 6) + l15) << 6;

  // ---- prologue: X(chunk 0) + A(ph=0) -> buf0, full drain ----
#pragma unroll
  for (int it = 0; it < 7; ++it)
    async16(xg[it], (char*)sX + it * 4096 + (wid << 10));
#pragma unroll
  for (int it = 0; it < 4; ++it)
    async16(wtb + aoff0 + it * 16384, (char*)sAe + it * 4096 + (wid << 10));
  asm volatile("s_waitcnt vmcnt(0)" ::: "memory");
  __builtin_amdgcn_sched_barrier(0);
  __builtin_amdgcn_s_barrier();

  for (int icb = 0; icb < 8; ++icb) {
    const int ic = icb << 6;
#pragma unroll
    for (int t = 0; t < 9; ++t) {
      const int cur = (icb + t) & 1;  // ph & 1, ph = icb*9+t
      // ---- X restage for THIS chunk (older than A(ph+1) in queue) ----
      if (t == 0 && icb > 0) {
#pragma unroll
        for (int it = 0; it < 7; ++it)
          async16(xg[it] + ic, (char*)sX + it * 4096 + (wid << 10));
      }
      // ---- issue A(ph+1) into the other buffer ----
      if (!(icb == 7 && t == 8)) {
        const int tn = (t == 8) ? 0 : t + 1;
        const int icn = ic + ((t == 8) ? 64 : 0);
        const __bf16* wa = wtb + tn * 262144 + icn + aoff0;
        char* dst = (char*)sAe + (cur ^ 1) * 16384 + (wid << 10);
#pragma unroll
        for (int it = 0; it < 4; ++it) async16(wa + it * 16384, dst + it * 4096);
      }
      // ---- counted wait: A(ph) [+X at t==0] done; A(ph+1) in flight ----
      if (icb == 7 && t == 8) {
        asm volatile("s_waitcnt vmcnt(0)" ::: "memory");
      } else {
        asm volatile("s_waitcnt vmcnt(4)" ::: "memory");
      }
      __builtin_amdgcn_sched_barrier(0);
      __builtin_amdgcn_s_barrier();
      __builtin_amdgcn_sched_barrier(0);
      // ---- compute tap t from sAe[cur], sX ----
      const int ky = t / 3, kx = t - (t / 3) * 3;
      const __bf16* sAb = sAe + cur * 8192;
      __builtin_amdgcn_s_setprio(1);
#pragma unroll
      for (int kk = 0; kk < 2; ++kk) {
        const int jb = lq + (kk << 2);
        const int jA = (jb ^ l7) << 3;
        bf16x8 af[4], bfr[4];
#pragma unroll
        for (int m = 0; m < 4; ++m)
          af[m] = *(const bf16x8*)&sAb[arowb + (m << 10) + jA];
#pragma unroll
        for (int n = 0; n < 4; ++n) {
          int p = (prn[n] + ky) * 34 + pcn[n] + kx;
          bfr[n] = *(const bf16x8*)&sX[(p << 6) + ((jb ^ (p & 7)) << 3)];
        }
#pragma unroll
        for (int m = 0; m < 4; ++m)
#pragma unroll
          for (int n = 0; n < 4; ++n)
            acc[m][n] = __builtin_amdgcn_mfma_f32_16x16x32_bf16(af[m], bfr[n],
                                                                acc[m][n], 0, 0, 0);
      }
      __builtin_amdgcn_s_setprio(0);
      __builtin_amdgcn_sched_barrier(0);
      __builtin_amdgcn_s_barrier();
    }
  }

  // Epilogue: C/D col=lane&15 (pixel), row=(lane>>4)*4+q (out chan).
  float* outb = out + ((long)b << 21);
#pragma unroll
  for (int m = 0; m < 4; ++m) {
    int ob = o0 + (wr << 6) + (m << 4) + (lq << 2);
#pragma unroll
    for (int n = 0; n < 4; ++n) {
      int h = h0 + prn[n], w = w0 + pcn[n];
#pragma unroll
      for (int q = 0; q < 4; ++q) {
        int o = ob + q;
        outb[((long)o << 12) + (h << 6) + w] = acc[m][n][q] + bias[o];
      }
    }
  }
}

extern "C" void kernel_launch(void* const* d_in, const int* in_sizes, int n_in,
                              void* d_out, int out_size, void* d_ws, size_t ws_size,
                              hipStream_t stream) {
  const float* imgs = (const float*)d_in[0];
  const float* w_embs = (const float*)d_in[1];
  const float* cw = (const float*)d_in[2];
  const float* bias = (const float*)d_in[3];
  const float* style_W = (const float*)d_in[4];
  const float* style_b = (const float*)d_in[5];
  float* out = (float*)d_out;

  char* ws = (char*)d_ws;
  float* style = (float*)(ws);                          // 32 KB
  float* rnorm = (float*)(ws + (32 << 10));             // 32 KB
  float* wsq = (float*)(ws + (64 << 10));               // 1 MB
  __bf16* wt = (__bf16*)(ws + (64 << 10) + (1 << 20));  // 75,497,472 B
  __bf16* xpad = (__bf16*)(ws + (64 << 10) + (1 << 20) + 75497472);  // 71,368,704 B
  size_t need = (size_t)(64 << 10) + (1 << 20) + 75497472ull + 71368704ull;
  if (ws_size < need) return;  // leaves d_out poisoned -> visible failure mode

  k_style<<<2048, 256, 0, stream>>>(w_embs, style_W, style_b, style);
  k_wsq<<<1024, 256, 0, stream>>>(cw, wsq);
  k_rnorm<<<2048, 256, 0, stream>>>(style, wsq, rnorm);
  k_wt<<<16384, 256, 0, stream>>>(cw, style, rnorm, wt);
  k_xpad<<<273, 256, 0, stream>>>(imgs, xpad);
  k_conv<<<2048, 256, 0, stream>>>(xpad, wt, bias, out);
}